// Round 1
// baseline (357.814 us; speedup 1.0000x reference)
//
#include <hip/hip_runtime.h>

typedef unsigned short u16;
typedef __attribute__((ext_vector_type(8))) short bf16x8;  // 8 bf16 in 4 VGPRs
typedef __attribute__((ext_vector_type(4))) float f32x4;

constexpr int BATCH = 8192;
constexpr int UNITS = 1024;
constexpr int K2    = 2048;   // combined K  ([x | h_prev])
constexpr int N4    = 4096;   // 4*UNITS gate columns

__device__ __forceinline__ u16 f2bf(float f) {
  unsigned u = __float_as_uint(f);
  u += 0x7fffu + ((u >> 16) & 1u);   // round-to-nearest-even
  return (u16)(u >> 16);
}

__device__ __forceinline__ void async_copy16(const void* g, void* l) {
  __builtin_amdgcn_global_load_lds(
      (const __attribute__((address_space(1))) void*)g,
      (__attribute__((address_space(3))) void*)l, 16, 0, 0);
}

// ---------------------------------------------------------------------------
// Pack A = [x | h_prev] as bf16, row-major [8192][2048]
// ---------------------------------------------------------------------------
__global__ void cast_a_kernel(const float* __restrict__ x,
                              const float* __restrict__ h,
                              u16* __restrict__ A) {
  int t = blockIdx.x * blockDim.x + threadIdx.x;   // one thread per 4 elems
  int idx = t * 4;
  int b = idx >> 11;          // / 2048
  int k = idx & 2047;
  const float* src = (k < UNITS) ? (x + (size_t)b * UNITS + k)
                                 : (h + (size_t)b * UNITS + (k - UNITS));
  float4 v = *reinterpret_cast<const float4*>(src);
  union { ushort4 u4; u16 s[4]; } o;
  o.s[0] = f2bf(v.x); o.s[1] = f2bf(v.y); o.s[2] = f2bf(v.z); o.s[3] = f2bf(v.w);
  *reinterpret_cast<ushort4*>(A + idx) = o.u4;
}

// ---------------------------------------------------------------------------
// Pack B^T (permuted) as bf16 [4096 p][2048 k]:
//   B[p][k] = src[k][oc(p)],  oc(p) = jn*1024 + (p>>6)*16 + (p&15),
//   jn = (p>>4)&3  (gate index),  src = W rows 0..1023, U rows 1024..2047.
// Column permutation makes each wave's 4 column-tiles = the 4 gates of the
// same 16 units, so the LSTM epilogue fuses in-register.
// ---------------------------------------------------------------------------
__global__ void cast_b_kernel(const float* __restrict__ W,
                              const float* __restrict__ U,
                              u16* __restrict__ B) {
  __shared__ float lds[64 * 17];          // 64 k-rows x 16 n-cols, padded
  const int p0 = blockIdx.x * 16;         // 16 consecutive p (same q, jn)
  const int k0 = blockIdx.y * 64;
  const int q  = p0 >> 6;
  const int jn = (p0 >> 4) & 3;
  const int n0 = jn * UNITS + q * 16;
  const float* src = (k0 < UNITS) ? (W + (size_t)k0 * N4)
                                  : (U + (size_t)(k0 - UNITS) * N4);
  const int tid = threadIdx.x;
  // phase 1: coalesced read of [64 k][16 n]
  {
    int nn = tid & 15, kb = tid >> 4;     // kb 0..15
#pragma unroll
    for (int r = 0; r < 4; ++r) {
      int kk = kb + r * 16;
      lds[kk * 17 + nn] = src[(size_t)kk * N4 + n0 + nn];
    }
  }
  __syncthreads();
  // phase 2: write [16 p][64 k], 4 bf16 (8B) per thread, coalesced
  {
    int kk4 = (tid & 15) * 4, pp = tid >> 4;
    union { ushort4 u4; u16 s[4]; } o;
#pragma unroll
    for (int j = 0; j < 4; ++j) o.s[j] = f2bf(lds[(kk4 + j) * 17 + pp]);
    *reinterpret_cast<ushort4*>(&B[(size_t)(p0 + pp) * K2 + k0 + kk4]) = o.u4;
  }
}

// ---------------------------------------------------------------------------
// Fused GEMM + peephole LSTM cell.
// Z[m][p] = sum_k A[m][k]*B[p][k]  (p is the permuted gate-column space)
// 128x128 tile, BK=32, 4 waves, 4x4 mfma_f32_16x16x32_bf16 per wave.
// Wave's column-tile index jn == gate (f,i,c,o). Epilogue in-register.
// ---------------------------------------------------------------------------
__global__ __launch_bounds__(256) void lstm_gemm_kernel(
    const u16* __restrict__ A, const u16* __restrict__ B,
    const float* __restrict__ bias, const float* __restrict__ c_prev,
    const float* __restrict__ pf, const float* __restrict__ pi,
    const float* __restrict__ po,
    float* __restrict__ out_h, float* __restrict__ out_c) {
  __shared__ u16 As[128 * 32];   // 8 KB
  __shared__ u16 Bs[128 * 32];   // 8 KB

  const int tid  = threadIdx.x;
  const int lane = tid & 63;
  const int wave = tid >> 6;
  const int quad = lane >> 4;
  const int c    = lane & 15;
  const int m0   = blockIdx.y * 128;
  const int n0   = blockIdx.x * 128;
  const int wm   = (wave >> 1) * 64;
  const int wn   = (wave & 1) * 64;

  // staging: 512 16B-chunks per tile; chunk f -> row f>>2, k-group (f&3)*8.
  // wave w stages chunks [w*128, w*128+64) and [w*128+64, w*128+128).
  const int f0   = wave * 128 + lane;
  const int row0 = f0 >> 2;
  const int kq   = (f0 & 3) * 8;
  const u16* ga0 = A + (size_t)(m0 + row0) * K2 + kq;
  const u16* ga1 = ga0 + (size_t)16 * K2;
  const u16* gb0 = B + (size_t)(n0 + row0) * K2 + kq;
  const u16* gb1 = gb0 + (size_t)16 * K2;
  u16* la0 = &As[(wave * 2 + 0) * 512];
  u16* la1 = &As[(wave * 2 + 1) * 512];
  u16* lb0 = &Bs[(wave * 2 + 0) * 512];
  u16* lb1 = &Bs[(wave * 2 + 1) * 512];

  f32x4 acc[4][4] = {};

  for (int kt = 0; kt < K2 / 32; ++kt) {
    async_copy16(ga0, la0);
    async_copy16(ga1, la1);
    async_copy16(gb0, lb0);
    async_copy16(gb1, lb1);
    ga0 += 32; ga1 += 32; gb0 += 32; gb1 += 32;
    __syncthreads();   // drains vmcnt(0): staged LDS visible

    bf16x8 af[4], bfr[4];
#pragma unroll
    for (int j = 0; j < 4; ++j) {
      af[j]  = *(const bf16x8*)&As[(wm + j * 16 + c) * 32 + quad * 8];
      bfr[j] = *(const bf16x8*)&Bs[(wn + j * 16 + c) * 32 + quad * 8];
    }
#pragma unroll
    for (int jm = 0; jm < 4; ++jm)
#pragma unroll
      for (int jn = 0; jn < 4; ++jn)
        acc[jm][jn] = __builtin_amdgcn_mfma_f32_16x16x32_bf16(
            af[jm], bfr[jn], acc[jm][jn], 0, 0, 0);
    __syncthreads();   // all waves done reading before next stage overwrites
  }

  // ---- fused peephole-LSTM epilogue -------------------------------------
  // lane's unit: u = (n0+wn)/4 + c ; acc[jm][jn] holds gate jn for unit u.
  const int u = ((n0 + wn) >> 2) + c;
  const float bf_ = bias[u];
  const float bi_ = bias[UNITS + u];
  const float bc_ = bias[2 * UNITS + u];
  const float bo_ = bias[3 * UNITS + u];
  const float pfv = pf[u], piv = pi[u], pov = po[u];
  const int mbase = m0 + wm + quad * 4;
#pragma unroll
  for (int jm = 0; jm < 4; ++jm) {
#pragma unroll
    for (int r = 0; r < 4; ++r) {
      const int b = mbase + jm * 16 + r;
      const float cp = c_prev[(size_t)b * UNITS + u];
      const float zf = acc[jm][0][r] + bf_ + pfv * cp;
      const float zi = acc[jm][1][r] + bi_ + piv * cp;
      const float zc = acc[jm][2][r] + bc_;
      const float zo = acc[jm][3][r] + bo_;
      const float fg = 1.f / (1.f + __expf(-zf));
      const float ig = 1.f / (1.f + __expf(-zi));
      const float ct = 1.f - 2.f / (__expf(2.f * zc) + 1.f);   // tanh, NaN-safe
      const float cn = fg * cp + ig * ct;
      const float og = 1.f / (1.f + __expf(-(zo + pov * cn)));
      const float hn = og * (1.f - 2.f / (__expf(2.f * cn) + 1.f));
      out_h[(size_t)b * UNITS + u] = hn;
      out_c[(size_t)b * UNITS + u] = cn;
    }
  }
}

// ---------------------------------------------------------------------------
extern "C" void kernel_launch(void* const* d_in, const int* in_sizes, int n_in,
                              void* d_out, int out_size, void* d_ws, size_t ws_size,
                              hipStream_t stream) {
  const float* x      = (const float*)d_in[0];   // [8192,1024]
  const float* c_prev = (const float*)d_in[1];   // [8192,1024]
  const float* h_prev = (const float*)d_in[2];   // [8192,1024]
  const float* W      = (const float*)d_in[3];   // [1024,4096]
  const float* U      = (const float*)d_in[4];   // [1024,4096]
  const float* bias   = (const float*)d_in[5];   // [4096]
  const float* pf     = (const float*)d_in[6];   // [1024]
  const float* pi     = (const float*)d_in[7];
  const float* po     = (const float*)d_in[8];
  float* out_h = (float*)d_out;
  float* out_c = out_h + (size_t)BATCH * UNITS;

  u16* Abf = (u16*)d_ws;                           // 32 MB
  u16* Bbf = Abf + (size_t)BATCH * K2;             // 16 MB

  // A pack: 8192*2048/4 threads
  cast_a_kernel<<<(BATCH * K2 / 4) / 256, 256, 0, stream>>>(x, h_prev, Abf);
  // B pack/transpose/permute: p-tiles x k-tiles
  cast_b_kernel<<<dim3(N4 / 16, K2 / 64), 256, 0, stream>>>(W, U, Bbf);
  // fused GEMM + LSTM
  lstm_gemm_kernel<<<dim3(N4 / 128, BATCH / 128), 256, 0, stream>>>(
      Abf, Bbf, bias, c_prev, pf, pi, po, out_h, out_c);
}

// Round 2
// 349.022 us; speedup vs baseline: 1.0252x; 1.0252x over previous
//
#include <hip/hip_runtime.h>

typedef unsigned short u16;
typedef __attribute__((ext_vector_type(8))) short bf16x8;  // 8 bf16 in 4 VGPRs
typedef __attribute__((ext_vector_type(4))) float f32x4;

constexpr int BATCH = 8192;
constexpr int UNITS = 1024;
constexpr int K2    = 2048;   // combined K  ([x | h_prev])
constexpr int N4    = 4096;   // 4*UNITS gate columns

__device__ __forceinline__ u16 f2bf(float f) {
  unsigned u = __float_as_uint(f);
  u += 0x7fffu + ((u >> 16) & 1u);   // round-to-nearest-even
  return (u16)(u >> 16);
}

__device__ __forceinline__ void async_copy16(const void* g, void* l) {
  __builtin_amdgcn_global_load_lds(
      (const __attribute__((address_space(1))) void*)g,
      (__attribute__((address_space(3))) void*)l, 16, 0, 0);
}

// ---------------------------------------------------------------------------
// Fused cast kernel.
//   blocks [0, 2048):    B pack/transpose/permute  (64n x 64k tile per block)
//   blocks [2048, 6144): A = [x | h_prev] bf16 pack (grid-stride float4)
//
// B layout produced: bf16 [4096 p][2048 k],
//   B[p][k] = src[k][oc(p)], oc(p) = jn*1024 + (p>>6)*16 + (p&15), jn=(p>>4)&3
// so each GEMM wave's 4 column-tiles are the 4 gates of the same 16 units.
// ---------------------------------------------------------------------------
__global__ __launch_bounds__(256) void cast_fused_kernel(
    const float* __restrict__ x, const float* __restrict__ h,
    const float* __restrict__ W, const float* __restrict__ U,
    u16* __restrict__ A, u16* __restrict__ B) {
  const int tid = threadIdx.x;
  if (blockIdx.x < 2048) {
    // ---- B pack: tile n0..n0+63 (one gate), k0..k0+63 ----
    __shared__ float lds[64 * 69];        // pad 69: phase2 col-reads 2-way only
    const int bid = blockIdx.x;
    const int nb  = bid & 63;             // 64 n-tiles
    const int kb  = bid >> 6;             // 32 k-tiles
    const int n0  = nb * 64;
    const int k0  = kb * 64;
    const int jn  = n0 >> 10;             // gate index
    const int q0  = (n0 & 1023) >> 4;     // base unit-group (4 consecutive)
    const float* src = (k0 < UNITS) ? (W + (size_t)k0 * N4)
                                    : (U + (size_t)(k0 - UNITS) * N4);
    // phase 1: read [64 k][64 n], 256B contiguous per row-segment
    {
      const int kk  = tid >> 4;           // 16 rows per pass
      const int nn4 = (tid & 15) * 4;
#pragma unroll
      for (int r = 0; r < 4; ++r) {
        const int k = kk + r * 16;
        float4 v = *reinterpret_cast<const float4*>(&src[(size_t)k * N4 + n0 + nn4]);
        lds[k * 69 + nn4 + 0] = v.x;
        lds[k * 69 + nn4 + 1] = v.y;
        lds[k * 69 + nn4 + 2] = v.z;
        lds[k * 69 + nn4 + 3] = v.w;
      }
    }
    __syncthreads();
    // phase 2: write 64 p-rows x 64 k, 8B/thread, 128B contiguous per p-row
    {
      const int kk4 = (tid & 15) * 4;
#pragma unroll
      for (int pass = 0; pass < 4; ++pass) {
        const int rr  = (tid >> 4) + pass * 16;   // 0..63, orig col = n0 + rr
        const int q   = q0 + (rr >> 4);
        const int low = rr & 15;
        const int p   = q * 64 + jn * 16 + low;
        union { ushort4 u4; u16 s[4]; } o;
#pragma unroll
        for (int j = 0; j < 4; ++j) o.s[j] = f2bf(lds[(kk4 + j) * 69 + rr]);
        *reinterpret_cast<ushort4*>(&B[(size_t)p * K2 + k0 + kk4]) = o.u4;
      }
    }
  } else {
    // ---- A pack: grid-stride, 4 float4 groups per thread ----
    const int t0 = (blockIdx.x - 2048) * 256 + tid;
    const int stride = 4096 * 256;
#pragma unroll
    for (int s = 0; s < 4; ++s) {
      const int g = t0 + s * stride;
      const int idx = g * 4;
      const int b = idx >> 11;
      const int k = idx & 2047;
      const float* src = (k < UNITS) ? (x + (size_t)b * UNITS + k)
                                     : (h + (size_t)b * UNITS + (k - UNITS));
      float4 v = *reinterpret_cast<const float4*>(src);
      union { ushort4 u4; u16 sv[4]; } o;
      o.sv[0] = f2bf(v.x); o.sv[1] = f2bf(v.y);
      o.sv[2] = f2bf(v.z); o.sv[3] = f2bf(v.w);
      *reinterpret_cast<ushort4*>(A + idx) = o.u4;
    }
  }
}

// ---------------------------------------------------------------------------
// Fused GEMM + peephole LSTM cell.
// 128x128 tile, BK=32, 4 waves, 4x4 mfma_f32_16x16x32_bf16 per wave.
// LDS k-slot XOR swizzle: row r slot s holds k-group g = s ^ ((r>>1)&3),
// making both staging writes and ds_read_b128 fragment reads 2-way (free).
// ---------------------------------------------------------------------------
__global__ __launch_bounds__(256) void lstm_gemm_kernel(
    const u16* __restrict__ A, const u16* __restrict__ B,
    const float* __restrict__ bias, const float* __restrict__ c_prev,
    const float* __restrict__ pf, const float* __restrict__ pi,
    const float* __restrict__ po,
    float* __restrict__ out_h, float* __restrict__ out_c) {
  __shared__ u16 As[128 * 32];   // 8 KB
  __shared__ u16 Bs[128 * 32];   // 8 KB

  const int tid  = threadIdx.x;
  const int lane = tid & 63;
  const int wave = tid >> 6;
  const int quad = lane >> 4;
  const int c    = lane & 15;
  const int m0   = blockIdx.y * 128;
  const int n0   = blockIdx.x * 128;
  const int wm   = (wave >> 1) * 64;
  const int wn   = (wave & 1) * 64;

  // staging with XOR swizzle: lane's chunk f = wave*128 + lane (+64 for 2nd),
  // row = f>>2, LDS slot = f&3; fetch k-group g = (f&3) ^ ((row>>1)&3)
  //   = (lane&3) ^ ((lane>>3)&3)  (same for both chunks; see derivation).
  const int f0   = wave * 128 + lane;
  const int row0 = f0 >> 2;
  const int kq   = ((lane & 3) ^ ((lane >> 3) & 3)) * 8;
  const u16* ga0 = A + (size_t)(m0 + row0) * K2 + kq;
  const u16* ga1 = ga0 + (size_t)16 * K2;
  const u16* gb0 = B + (size_t)(n0 + row0) * K2 + kq;
  const u16* gb1 = gb0 + (size_t)16 * K2;
  u16* la0 = &As[(wave * 2 + 0) * 512];
  u16* la1 = &As[(wave * 2 + 1) * 512];
  u16* lb0 = &Bs[(wave * 2 + 0) * 512];
  u16* lb1 = &Bs[(wave * 2 + 1) * 512];

  f32x4 acc[4][4] = {};

  for (int kt = 0; kt < K2 / 32; ++kt) {
    async_copy16(ga0, la0);
    async_copy16(ga1, la1);
    async_copy16(gb0, lb0);
    async_copy16(gb1, lb1);
    ga0 += 32; ga1 += 32; gb0 += 32; gb1 += 32;
    __syncthreads();   // drains vmcnt(0): staged LDS visible

    bf16x8 af[4], bfr[4];
#pragma unroll
    for (int j = 0; j < 4; ++j) {
      const int ra = wm + j * 16 + c;
      const int rb = wn + j * 16 + c;
      const int sl = (quad ^ ((c >> 1) & 3)) * 8;   // swizzled k-slot
      af[j]  = *(const bf16x8*)&As[ra * 32 + sl];
      bfr[j] = *(const bf16x8*)&Bs[rb * 32 + sl];
    }
#pragma unroll
    for (int jm = 0; jm < 4; ++jm)
#pragma unroll
      for (int jn = 0; jn < 4; ++jn)
        acc[jm][jn] = __builtin_amdgcn_mfma_f32_16x16x32_bf16(
            af[jm], bfr[jn], acc[jm][jn], 0, 0, 0);
    __syncthreads();   // all waves done reading before next stage overwrites
  }

  // ---- fused peephole-LSTM epilogue -------------------------------------
  // lane's unit: u = (n0+wn)/4 + c ; acc[jm][jn] holds gate jn for unit u.
  const int u = ((n0 + wn) >> 2) + c;
  const float bf_ = bias[u];
  const float bi_ = bias[UNITS + u];
  const float bc_ = bias[2 * UNITS + u];
  const float bo_ = bias[3 * UNITS + u];
  const float pfv = pf[u], piv = pi[u], pov = po[u];
  const int mbase = m0 + wm + quad * 4;
#pragma unroll
  for (int jm = 0; jm < 4; ++jm) {
#pragma unroll
    for (int r = 0; r < 4; ++r) {
      const int b = mbase + jm * 16 + r;
      const float cp = c_prev[(size_t)b * UNITS + u];
      const float zf = acc[jm][0][r] + bf_ + pfv * cp;
      const float zi = acc[jm][1][r] + bi_ + piv * cp;
      const float zc = acc[jm][2][r] + bc_;
      const float zo = acc[jm][3][r] + bo_;
      const float fg = 1.f / (1.f + __expf(-zf));
      const float ig = 1.f / (1.f + __expf(-zi));
      const float ct = 1.f - 2.f / (__expf(2.f * zc) + 1.f);   // tanh, NaN-safe
      const float cn = fg * cp + ig * ct;
      const float og = 1.f / (1.f + __expf(-(zo + pov * cn)));
      const float hn = og * (1.f - 2.f / (__expf(2.f * cn) + 1.f));
      out_h[(size_t)b * UNITS + u] = hn;
      out_c[(size_t)b * UNITS + u] = cn;
    }
  }
}

// ---------------------------------------------------------------------------
extern "C" void kernel_launch(void* const* d_in, const int* in_sizes, int n_in,
                              void* d_out, int out_size, void* d_ws, size_t ws_size,
                              hipStream_t stream) {
  const float* x      = (const float*)d_in[0];   // [8192,1024]
  const float* c_prev = (const float*)d_in[1];   // [8192,1024]
  const float* h_prev = (const float*)d_in[2];   // [8192,1024]
  const float* W      = (const float*)d_in[3];   // [1024,4096]
  const float* U      = (const float*)d_in[4];   // [1024,4096]
  const float* bias   = (const float*)d_in[5];   // [4096]
  const float* pf     = (const float*)d_in[6];   // [1024]
  const float* pi     = (const float*)d_in[7];
  const float* po     = (const float*)d_in[8];
  float* out_h = (float*)d_out;
  float* out_c = out_h + (size_t)BATCH * UNITS;

  u16* Abf = (u16*)d_ws;                           // 32 MB
  u16* Bbf = Abf + (size_t)BATCH * K2;             // 16 MB

  // one fused cast launch: 2048 B-blocks + 4096 A-blocks
  cast_fused_kernel<<<6144, 256, 0, stream>>>(x, h_prev, W, U, Abf, Bbf);
  // fused GEMM + LSTM
  lstm_gemm_kernel<<<dim3(N4 / 128, BATCH / 128), 256, 0, stream>>>(
      Abf, Bbf, bias, c_prev, pf, pi, po, out_h, out_c);
}

// Round 3
// 335.306 us; speedup vs baseline: 1.0671x; 1.0409x over previous
//
#include <hip/hip_runtime.h>

typedef unsigned short u16;
typedef __attribute__((ext_vector_type(8))) short bf16x8;  // 8 bf16 in 4 VGPRs
typedef __attribute__((ext_vector_type(4))) float f32x4;

constexpr int BATCH = 8192;
constexpr int UNITS = 1024;
constexpr int K2    = 2048;   // combined K  ([x | h_prev])
constexpr int N4    = 4096;   // 4*UNITS gate columns
constexpr int BK    = 64;     // K-tile per barrier pair

__device__ __forceinline__ u16 f2bf(float f) {
  unsigned u = __float_as_uint(f);
  u += 0x7fffu + ((u >> 16) & 1u);   // round-to-nearest-even
  return (u16)(u >> 16);
}

__device__ __forceinline__ void async_copy16(const void* g, void* l) {
  __builtin_amdgcn_global_load_lds(
      (const __attribute__((address_space(1))) void*)g,
      (__attribute__((address_space(3))) void*)l, 16, 0, 0);
}

// ---------------------------------------------------------------------------
// Fused cast kernel (unchanged from R2 — worked, conflict-free).
//   blocks [0, 2048):    B pack/transpose/permute  (64n x 64k tile per block)
//   blocks [2048, 6144): A = [x | h_prev] bf16 pack (grid-stride float4)
// B layout: bf16 [4096 p][2048 k], B[p][k] = src[k][oc(p)],
//   oc(p) = jn*1024 + (p>>6)*16 + (p&15), jn = (p>>4)&3  → each GEMM wave's
//   4 column-tiles are the 4 gates of the same 16 units.
// ---------------------------------------------------------------------------
__global__ __launch_bounds__(256) void cast_fused_kernel(
    const float* __restrict__ x, const float* __restrict__ h,
    const float* __restrict__ W, const float* __restrict__ U,
    u16* __restrict__ A, u16* __restrict__ B) {
  const int tid = threadIdx.x;
  if (blockIdx.x < 2048) {
    __shared__ float lds[64 * 69];
    const int bid = blockIdx.x;
    const int nb  = bid & 63;
    const int kb  = bid >> 6;
    const int n0  = nb * 64;
    const int k0  = kb * 64;
    const int jn  = n0 >> 10;
    const int q0  = (n0 & 1023) >> 4;
    const float* src = (k0 < UNITS) ? (W + (size_t)k0 * N4)
                                    : (U + (size_t)(k0 - UNITS) * N4);
    {
      const int kk  = tid >> 4;
      const int nn4 = (tid & 15) * 4;
#pragma unroll
      for (int r = 0; r < 4; ++r) {
        const int k = kk + r * 16;
        float4 v = *reinterpret_cast<const float4*>(&src[(size_t)k * N4 + n0 + nn4]);
        lds[k * 69 + nn4 + 0] = v.x;
        lds[k * 69 + nn4 + 1] = v.y;
        lds[k * 69 + nn4 + 2] = v.z;
        lds[k * 69 + nn4 + 3] = v.w;
      }
    }
    __syncthreads();
    {
      const int kk4 = (tid & 15) * 4;
#pragma unroll
      for (int pass = 0; pass < 4; ++pass) {
        const int rr  = (tid >> 4) + pass * 16;
        const int q   = q0 + (rr >> 4);
        const int low = rr & 15;
        const int p   = q * 64 + jn * 16 + low;
        union { ushort4 u4; u16 s[4]; } o;
#pragma unroll
        for (int j = 0; j < 4; ++j) o.s[j] = f2bf(lds[(kk4 + j) * 69 + rr]);
        *reinterpret_cast<ushort4*>(&B[(size_t)p * K2 + k0 + kk4]) = o.u4;
      }
    }
  } else {
    const int t0 = (blockIdx.x - 2048) * 256 + tid;
    const int stride = 4096 * 256;
#pragma unroll
    for (int s = 0; s < 4; ++s) {
      const int g = t0 + s * stride;
      const int idx = g * 4;
      const int b = idx >> 11;
      const int k = idx & 2047;
      const float* src = (k < UNITS) ? (x + (size_t)b * UNITS + k)
                                     : (h + (size_t)b * UNITS + (k - UNITS));
      float4 v = *reinterpret_cast<const float4*>(src);
      union { ushort4 u4; u16 sv[4]; } o;
      o.sv[0] = f2bf(v.x); o.sv[1] = f2bf(v.y);
      o.sv[2] = f2bf(v.z); o.sv[3] = f2bf(v.w);
      *reinterpret_cast<ushort4*>(A + idx) = o.u4;
    }
  }
}

// ---------------------------------------------------------------------------
// Fused GEMM + peephole LSTM cell.  BK=64: 32 iterations, 2 barriers each.
// LDS row = 64 u16 = 8 slots of 16B; k-group g stored at slot g^(row&7):
//  - staging lane fetches k-group (lane&7)^((lane>>3)&7), dest lane-linear
//  - fragment read slot (ks*4+quad)^(c&7) → uniform 8 lanes/bank-quad, 0-conflict
// ---------------------------------------------------------------------------
__global__ __launch_bounds__(256, 4) void lstm_gemm_kernel(
    const u16* __restrict__ A, const u16* __restrict__ B,
    const float* __restrict__ bias, const float* __restrict__ c_prev,
    const float* __restrict__ pf, const float* __restrict__ pi,
    const float* __restrict__ po,
    float* __restrict__ out_h, float* __restrict__ out_c) {
  __shared__ u16 As[128 * BK];   // 16 KB
  __shared__ u16 Bs[128 * BK];   // 16 KB

  const int tid  = threadIdx.x;
  const int lane = tid & 63;
  const int wave = tid >> 6;
  const int quad = lane >> 4;
  const int c    = lane & 15;
  const int m0   = blockIdx.y * 128;
  const int n0   = blockIdx.x * 128;
  const int wm   = (wave >> 1) * 64;
  const int wn   = (wave & 1) * 64;

  // staging: thread's 4 chunks per matrix; chunk i → row wave*32+i*8+(lane>>3),
  // k-group g = (lane&7)^((lane>>3)&7) (same for all 4 chunks), dest f*16B linear.
  const int g8 = ((lane & 7) ^ ((lane >> 3) & 7)) * 8;
  const int r0 = wave * 32 + (lane >> 3);
  const u16* ga = A + (size_t)(m0 + r0) * K2 + g8;
  const u16* gb = B + (size_t)(n0 + r0) * K2 + g8;
  u16* la = &As[(wave * 256 + lane) * 8];
  u16* lb = &Bs[(wave * 256 + lane) * 8];

  f32x4 acc[4][4] = {};

  for (int kt = 0; kt < K2 / BK; ++kt) {
#pragma unroll
    for (int i = 0; i < 4; ++i) {
      async_copy16(ga + (size_t)i * 8 * K2, la + i * 512);
      async_copy16(gb + (size_t)i * 8 * K2, lb + i * 512);
    }
    ga += BK; gb += BK;
    __syncthreads();   // drains vmcnt(0): staged LDS visible

#pragma unroll
    for (int ks = 0; ks < 2; ++ks) {
      bf16x8 af[4], bfr[4];
#pragma unroll
      for (int j = 0; j < 4; ++j) {
        const int sl = ((ks * 4 + quad) ^ (c & 7)) * 8;
        af[j]  = *(const bf16x8*)&As[(wm + j * 16 + c) * BK + sl];
        bfr[j] = *(const bf16x8*)&Bs[(wn + j * 16 + c) * BK + sl];
      }
#pragma unroll
      for (int jm = 0; jm < 4; ++jm)
#pragma unroll
        for (int jn = 0; jn < 4; ++jn)
          acc[jm][jn] = __builtin_amdgcn_mfma_f32_16x16x32_bf16(
              af[jm], bfr[jn], acc[jm][jn], 0, 0, 0);
    }
    __syncthreads();   // all waves done reading before next stage overwrites
  }

  // ---- fused peephole-LSTM epilogue -------------------------------------
  const int u = ((n0 + wn) >> 2) + c;
  const float bf_ = bias[u];
  const float bi_ = bias[UNITS + u];
  const float bc_ = bias[2 * UNITS + u];
  const float bo_ = bias[3 * UNITS + u];
  const float pfv = pf[u], piv = pi[u], pov = po[u];
  const int mbase = m0 + wm + quad * 4;
#pragma unroll
  for (int jm = 0; jm < 4; ++jm) {
#pragma unroll
    for (int r = 0; r < 4; ++r) {
      const int b = mbase + jm * 16 + r;
      const float cp = c_prev[(size_t)b * UNITS + u];
      const float zf = acc[jm][0][r] + bf_ + pfv * cp;
      const float zi = acc[jm][1][r] + bi_ + piv * cp;
      const float zc = acc[jm][2][r] + bc_;
      const float zo = acc[jm][3][r] + bo_;
      const float fg = 1.f / (1.f + __expf(-zf));
      const float ig = 1.f / (1.f + __expf(-zi));
      const float ct = 1.f - 2.f / (__expf(2.f * zc) + 1.f);   // tanh, NaN-safe
      const float cn = fg * cp + ig * ct;
      const float og = 1.f / (1.f + __expf(-(zo + pov * cn)));
      const float hn = og * (1.f - 2.f / (__expf(2.f * cn) + 1.f));
      out_h[(size_t)b * UNITS + u] = hn;
      out_c[(size_t)b * UNITS + u] = cn;
    }
  }
}

// ---------------------------------------------------------------------------
extern "C" void kernel_launch(void* const* d_in, const int* in_sizes, int n_in,
                              void* d_out, int out_size, void* d_ws, size_t ws_size,
                              hipStream_t stream) {
  const float* x      = (const float*)d_in[0];   // [8192,1024]
  const float* c_prev = (const float*)d_in[1];   // [8192,1024]
  const float* h_prev = (const float*)d_in[2];   // [8192,1024]
  const float* W      = (const float*)d_in[3];   // [1024,4096]
  const float* U      = (const float*)d_in[4];   // [1024,4096]
  const float* bias   = (const float*)d_in[5];   // [4096]
  const float* pf     = (const float*)d_in[6];   // [1024]
  const float* pi     = (const float*)d_in[7];
  const float* po     = (const float*)d_in[8];
  float* out_h = (float*)d_out;
  float* out_c = out_h + (size_t)BATCH * UNITS;

  u16* Abf = (u16*)d_ws;                           // 32 MB
  u16* Bbf = Abf + (size_t)BATCH * K2;             // 16 MB

  cast_fused_kernel<<<6144, 256, 0, stream>>>(x, h_prev, W, U, Abf, Bbf);
  lstm_gemm_kernel<<<dim3(N4 / 128, BATCH / 128), 256, 0, stream>>>(
      Abf, Bbf, bias, c_prev, pf, pi, po, out_h, out_c);
}